// Round 14
// baseline (351.247 us; speedup 1.0000x reference)
//
#include <hip/hip_runtime.h>

#define N_E   1024
#define E_DIM 512
#define HW_   4096
#define NVEC  65536                 // 16 * 64 * 64
#define ZQ_ELEMS 33554432           // 16*512*64*64
#define BETA 0.25f
#define DELTA 256.0f                // scaled (x1024) refine margin

typedef _Float16 half8 __attribute__((ext_vector_type(8), aligned(16)));
typedef float f32x4 __attribute__((ext_vector_type(4)));
typedef unsigned int u32x4 __attribute__((ext_vector_type(4), aligned(16)));

union H16 { _Float16 f; unsigned short u; };

// ---------------- ynorm (coalesced row reduce) ----------------
__global__ __launch_bounds__(64) void vq_prep(const float* __restrict__ cb,
    float* __restrict__ ynorm) {
    int j = blockIdx.x, l = threadIdx.x;
    float s = 0.f;
    for (int i = 0; i < 8; ++i) {
        float v = cb[(j << 9) + l + (i << 6)];
        s += v * v;
    }
#pragma unroll
    for (int off = 32; off > 0; off >>= 1) s += __shfl_xor(s, off);
    if (l == 0) ynorm[j] = s * 1024.f;        // scaled by 32^2 to match scaled dot
}

// ---------------- prepB: codebook -> Bf fragment-major fp16 HI only (x32) ----------------
// Per j16 block = 8192 halves (16 kchunks x 512): G = c*512 + lane*8 + e,
// j = j16*16 + (lane&15), k = c*32 + (lane>>4)*8 + e.
__global__ __launch_bounds__(256) void vq_prepB(const float* __restrict__ cb,
    unsigned short* __restrict__ Bf) {
    int j16 = blockIdx.x;                  // 64 blocks
    int t = threadIdx.x;
#pragma unroll
    for (int s = 0; s < 4; ++s) {
        int G = ((s << 8) + t) << 3;
        int c = G >> 9, w = G & 511;
        int lane = w >> 3;
        int j = (j16 << 4) + (lane & 15);
        int k0 = (c << 5) + ((lane >> 4) << 3);
        const float* p = cb + ((long)j << 9) + k0;
        unsigned short o8[8];
#pragma unroll
        for (int e = 0; e < 8; ++e) {
            H16 hh; hh.f = (_Float16)(32.f * p[e]);
            o8[e] = hh.u;
        }
        *(u32x4*)&Bf[((long)j16 << 13) + G] = *(u32x4*)&o8[0];
    }
}

// ---------------- fused: z->LDS fp16 staging + hi-only MFMA GEMM + top-2 argmin ----------------
// 512 blocks x 128 rows. 512 threads (8 waves: 2 m-groups x 4 j-quads).
// Pass 0: T14-staged transpose+convert of z into full-K LDS (one barrier/chunk),
// computing pass-0 MFMA and zpart on the way. Passes 1-3: barrier-free (A static in
// LDS, B register fragments from L2-resident Bf, per-wave-private LDS top-2 state).
__global__ __launch_bounds__(512, 2) void vq_fused(
    const float* __restrict__ z, const unsigned short* __restrict__ Bf,
    const float* __restrict__ ynorm, int* __restrict__ ws_idx,
    float* __restrict__ out_idx, float* __restrict__ bd1g,
    float* __restrict__ bd2g, int* __restrict__ bj2g,
    float* __restrict__ zpart) {

    __shared__ _Float16 sA[128][512];    // 128 KB; k-slot s' = (k>>3) ^ (row&7)
    __shared__ float b1d[128][4], b2d[128][4];
    __shared__ int   b1j[128][4], b2j[128][4];
    __shared__ float psum[8];

    const int t = threadIdx.x;
    const int l = t & 63, wid = t >> 6;
    const int lid = l & 15, kg = l >> 4;
    const int wm = (wid >> 2) << 6;      // 0 or 64
    const int jw = wid & 3;              // j-quad
    const int m0 = blockIdx.x << 7;      // 128 rows per block

    // wave-private best init (rows wm..wm+63, column jw)
    b1d[wm + l][jw] = 3.4e38f; b2d[wm + l][jw] = 3.4e38f;
    b1j[wm + l][jw] = 0x7fffffff; b2j[wm + l][jw] = 0x7fffffff;

    f32x4 acc[4][4];
    auto ZERO = [&]() {
#pragma unroll
        for (int mt = 0; mt < 4; ++mt)
#pragma unroll
            for (int jt = 0; jt < 4; ++jt) acc[mt][jt] = {0.f, 0.f, 0.f, 0.f};
    };

    auto COMPUTE = [&](int c, int p) {
        half8 ah[4];
#pragma unroll
        for (int mt = 0; mt < 4; ++mt) {
            int row = wm + (mt << 4) + lid;
            ah[mt] = *(const half8*)&sA[row][(((c << 2) + kg) ^ (row & 7)) << 3];
        }
        const unsigned short* bp = Bf + ((long)((p << 4) + (jw << 2)) << 13)
                                      + ((long)c << 9) + (l << 3);
#pragma unroll
        for (int jt = 0; jt < 4; ++jt) {
            half8 bh = *(const half8*)bp;
            bp += 8192;                   // next j16
#pragma unroll
            for (int mt = 0; mt < 4; ++mt)
                acc[mt][jt] = __builtin_amdgcn_mfma_f32_16x16x32_f16(ah[mt], bh, acc[mt][jt], 0, 0, 0);
        }
    };

    auto FOLD = [&](int p) {
        const int jgb = (p << 8) + (jw << 6);
        float yn[4];
#pragma unroll
        for (int jt = 0; jt < 4; ++jt) yn[jt] = ynorm[jgb + (jt << 4) + lid];
#pragma unroll
        for (int mt = 0; mt < 4; ++mt)
#pragma unroll
            for (int r = 0; r < 4; ++r) {
                float d1 = 3.4e38f, d2 = 3.4e38f;
                int i1 = 0x7fffffff, i2 = 0x7fffffff;
#pragma unroll
                for (int jt = 0; jt < 4; ++jt) {
                    int jg = jgb + (jt << 4) + lid;
                    float d = yn[jt] - 2.f * acc[mt][jt][r];
                    bool w = d < d1;
                    float c2 = w ? d1 : d;  int c2i = w ? i1 : jg;
                    d1 = w ? d : d1;        i1 = w ? jg : i1;
                    bool u = c2 < d2;
                    d2 = u ? c2 : d2;       i2 = u ? c2i : i2;
                }
#pragma unroll
                for (int off = 1; off < 16; off <<= 1) {
                    float e1 = __shfl_xor(d1, off), e2 = __shfl_xor(d2, off);
                    int   k1 = __shfl_xor(i1, off), k2 = __shfl_xor(i2, off);
                    bool w = e1 < d1;
                    float mx = w ? d1 : e1;  int nx = w ? i1 : k1;
                    d1 = w ? e1 : d1;        i1 = w ? k1 : i1;
                    bool a = e2 < d2;  float mm = a ? e2 : d2;  int nm = a ? k2 : i2;
                    bool bb = mx < mm;
                    d2 = bb ? mx : mm;  i2 = bb ? nx : nm;
                }
                if (lid == 0) {
                    int row = wm + (mt << 4) + (kg << 2) + r;
                    float D1 = b1d[row][jw], D2 = b2d[row][jw];
                    int   J1 = b1j[row][jw], J2 = b2j[row][jw];
                    bool w = d1 < D1;
                    float mx = w ? D1 : d1;  int nx = w ? J1 : i1;
                    float N1 = w ? d1 : D1;  int NJ1 = w ? i1 : J1;
                    bool a = d2 < D2;  float mm = a ? d2 : D2;  int nm = a ? i2 : J2;
                    bool bb = mx < mm;
                    b1d[row][jw] = N1;            b1j[row][jw] = NJ1;
                    b2d[row][jw] = bb ? mx : mm;  b2j[row][jw] = bb ? nx : nm;
                }
            }
    };

    // ---- pass 0: stage z -> sA (transpose + fp16 convert + zpart) while computing ----
    float zs = 0.f;
    const float* zb = z + ((long)(m0 >> 12) << 21) + (m0 & 4095);
    const int hwq = (t & 31) << 2;       // 4 consecutive rows (hw)
    const int cl  = t >> 5;              // 0..15: c-lane within chunk

    ZERO();
    float4 r0 = *(const float4*)&zb[((long)cl << 12) + hwq];
    float4 r1 = *(const float4*)&zb[((long)(cl + 16) << 12) + hwq];
    float4 n0 = {0, 0, 0, 0}, n1 = {0, 0, 0, 0};

    for (int c = 0; c < 16; ++c) {
        if (c < 15) {
            int cn = ((c + 1) << 5) + cl;
            n0 = *(const float4*)&zb[((long)cn << 12) + hwq];
            n1 = *(const float4*)&zb[((long)(cn + 16) << 12) + hwq];
        }
        const float* p0 = (const float*)&r0;
        const float* p1 = (const float*)&r1;
        int c0 = (c << 5) + cl, c1 = c0 + 16;
#pragma unroll
        for (int e = 0; e < 4; ++e) {
            int row = hwq + e;
            float v0 = p0[e], v1 = p1[e];
            zs += v0 * v0 + v1 * v1;
            sA[row][(((c0 >> 3) ^ (row & 7)) << 3) + (c0 & 7)] = (_Float16)(32.f * v0);
            sA[row][(((c1 >> 3) ^ (row & 7)) << 3) + (c1 & 7)] = (_Float16)(32.f * v1);
        }
        __syncthreads();                 // chunk c fully staged
        COMPUTE(c, 0);
        r0 = n0; r1 = n1;
    }
    FOLD(0); ZERO();

    // ---- passes 1-3: barrier-free ----
    for (int p = 1; p < 4; ++p) {
        for (int c = 0; c < 16; ++c) COMPUTE(c, p);
        FOLD(p); ZERO();
    }

    // ---- epilogue ----
#pragma unroll
    for (int off = 32; off > 0; off >>= 1) zs += __shfl_xor(zs, off);
    if (l == 0) psum[wid] = zs;
    __syncthreads();                     // b-best commits + psum visible

    if (t < 128) {
        float D1 = b1d[t][0], D2 = b2d[t][0];
        int   J1 = b1j[t][0], J2 = b2j[t][0];
#pragma unroll
        for (int w2 = 1; w2 < 4; ++w2) {
            float e1 = b1d[t][w2], e2 = b2d[t][w2];
            int   k1 = b1j[t][w2], k2 = b2j[t][w2];
            bool w = e1 < D1;
            float mx = w ? D1 : e1;  int nx = w ? J1 : k1;
            D1 = w ? e1 : D1;        J1 = w ? k1 : J1;
            bool a = e2 < D2;  float mm = a ? e2 : D2;  int nm = a ? k2 : J2;
            bool bb = mx < mm;
            D2 = bb ? mx : mm;  J2 = bb ? nx : nm;
        }
        int m = m0 + t;
        ws_idx[m]  = J1;
        out_idx[m] = (float)J1;
        bd1g[m] = D1; bd2g[m] = D2; bj2g[m] = J2;
    }
    if (t == 0) {
        float tot = 0.f;
#pragma unroll
        for (int i = 0; i < 8; ++i) tot += psum[i];
        zpart[blockIdx.x] = tot;
    }
}

// ---------------- refine: exact fp32 recheck of rows with hi-only gap <= DELTA ----------------
__global__ __launch_bounds__(256) void vq_refine(const float* __restrict__ z,
    const float* __restrict__ cb, const float* __restrict__ ynorm,
    const float* __restrict__ bd2, const int* __restrict__ bj2,
    int* __restrict__ ws_idx, float* __restrict__ out_idx, float* __restrict__ bd1) {
    int l = threadIdx.x & 63;
    int wv = (blockIdx.x << 2) + (threadIdx.x >> 6);   // 4096 waves
    for (int m = wv; m < NVEC; m += 4096) {
        float d1 = bd1[m];
        if (bd2[m] - d1 > DELTA) continue;             // certain: keep pass-1 result
        int j1 = ws_idx[m], j2 = bj2[m];
        const float* zr = z + ((long)(m >> 12) << 21) + (m & 4095);
        const float* c1 = cb + ((long)j1 << 9);
        const float* c2 = cb + ((long)j2 << 9);
        float s1 = 0.f, s2 = 0.f;
#pragma unroll
        for (int e = 0; e < 8; ++e) {
            int c = (l << 3) + e;
            float a = zr[(long)c << 12];
            s1 = fmaf(a, c1[c], s1);
            s2 = fmaf(a, c2[c], s2);
        }
#pragma unroll
        for (int off = 32; off > 0; off >>= 1) {
            s1 += __shfl_xor(s1, off);
            s2 += __shfl_xor(s2, off);
        }
        float de1 = ynorm[j1] - 2048.f * s1;           // scaled: 1024*(||y||^2 - 2 z.y)
        float de2 = ynorm[j2] - 2048.f * s2;
        bool take2 = de2 < de1 || (de2 == de1 && j2 < j1);
        if (l == 0) {
            if (take2) { ws_idx[m] = j2; out_idx[m] = (float)j2; bd1[m] = de2; }
            else       { bd1[m] = de1; }
        }
    }
}

// ---------------- gather: pure scatter of codebook rows into (B,C,H,W) ----------------
__global__ __launch_bounds__(256) void vq_gather(const float* __restrict__ cb,
    const int* __restrict__ ws_idx, float* __restrict__ out) {
    int base = blockIdx.x * 256 + threadIdx.x;   // 2^21 threads
    int hw  = base & 4095;
    int c4g = (base >> 12) & 31;
    int b   = base >> 17;
    int j   = ws_idx[(b << 12) | hw];
#pragma unroll
    for (int it = 0; it < 4; ++it) {
        int c4 = (c4g << 2) + it;
        float4 v = ((const float4*)cb)[(j << 7) + c4];
        long zo = ((long)((b << 9) + (c4 << 2))) * 4096 + hw;
        out[zo] = v.x; out[zo + 4096] = v.y; out[zo + 8192] = v.z; out[zo + 12288] = v.w;
    }
}

// ---------------- final: loss = 1.25 * (sum(bd1)/1024 + sum||z||^2) / numel ----------------
__global__ __launch_bounds__(1024) void vq_final(const float* __restrict__ bd1,
    const float* __restrict__ zpart, float* __restrict__ out) {
    int t = threadIdx.x;
    double s = 0.0;
#pragma unroll
    for (int i = 0; i < 64; ++i) s += (double)bd1[t + (i << 10)];
    s *= (1.0 / 1024.0);
    if (t < 512) s += (double)zpart[t];
#pragma unroll
    for (int off = 32; off > 0; off >>= 1) s += __shfl_xor(s, off);
    __shared__ double pd[16];
    if ((t & 63) == 0) pd[t >> 6] = s;
    __syncthreads();
    if (t == 0) {
        double tot = 0.0;
#pragma unroll
        for (int i = 0; i < 16; ++i) tot += pd[i];
        out[ZQ_ELEMS] = (float)(1.25 * tot / 33554432.0);
    }
}

extern "C" void kernel_launch(void* const* d_in, const int* in_sizes, int n_in,
                              void* d_out, int out_size, void* d_ws, size_t ws_size,
                              hipStream_t stream) {
    const float* z  = (const float*)d_in[0];   // (16,512,64,64) fp32
    const float* cb = (const float*)d_in[1];   // (1024,512) fp32
    float* out = (float*)d_out;                // [z_q | loss | indices(float)]
    char* ws = (char*)d_ws;

    float* ynorm = (float*)(ws + 1024);                   // 4 KB
    int*   ws_idx = (int*)(ws + 8192);                    // 256 KB
    float* bd1   = (float*)(ws + 272 * 1024);             // 256 KB
    float* bd2   = (float*)(ws + 528 * 1024);             // 256 KB
    int*   bj2   = (int*)(ws + 784 * 1024);               // 256 KB
    float* zpart = (float*)(ws + 1040 * 1024);            // 2 KB (512 floats)
    unsigned short* Bf = (unsigned short*)(ws + (2L << 20));   // 1 MB hi-only

    vq_prep<<<N_E, 64, 0, stream>>>(cb, ynorm);
    vq_prepB<<<64, 256, 0, stream>>>(cb, Bf);
    vq_fused<<<512, 512, 0, stream>>>(z, Bf, ynorm, ws_idx,
                                      out + ZQ_ELEMS + 1, bd1, bd2, bj2, zpart);
    vq_refine<<<1024, 256, 0, stream>>>(z, cb, ynorm, bd2, bj2, ws_idx,
                                        out + ZQ_ELEMS + 1, bd1);
    vq_gather<<<NVEC / 256 * 32, 256, 0, stream>>>(cb, ws_idx, out);
    vq_final<<<1, 1024, 0, stream>>>(bd1, zpart, out);
}

// Round 15
// 206.672 us; speedup vs baseline: 1.6995x; 1.6995x over previous
//
#include <hip/hip_runtime.h>

#define N_E   1024
#define E_DIM 512
#define HW_   4096
#define NVEC  65536                 // 16 * 64 * 64
#define ZQ_ELEMS 33554432           // 16*512*64*64
#define BETA 0.25f
#define DELTA 256.0f                // scaled (x1024) refine margin, ~6 sigma of hi-only diff error

typedef _Float16 half8 __attribute__((ext_vector_type(8), aligned(16)));
typedef float f32x4 __attribute__((ext_vector_type(4)));
typedef unsigned int u32x4 __attribute__((ext_vector_type(4), aligned(16)));

union H16 { _Float16 f; unsigned short u; };

// direct-to-LDS DMA: per-lane global src, wave-uniform LDS base + lane*16
#define GLDS(gp, lp) __builtin_amdgcn_global_load_lds( \
    (const __attribute__((address_space(1))) void*)(gp), \
    (__attribute__((address_space(3))) void*)(lp), 16, 0, 0)

// ---------------- ynorm (coalesced row reduce) ----------------
__global__ __launch_bounds__(64) void vq_prep(const float* __restrict__ cb,
    float* __restrict__ ynorm) {
    int j = blockIdx.x, l = threadIdx.x;
    float s = 0.f;
    for (int i = 0; i < 8; ++i) {
        float v = cb[(j << 9) + l + (i << 6)];
        s += v * v;
    }
#pragma unroll
    for (int off = 32; off > 0; off >>= 1) s += __shfl_xor(s, off);
    if (l == 0) ynorm[j] = s * 1024.f;        // scaled by 32^2 to match scaled dot
}

// ---------------- prepB: codebook -> Bf fragment-major fp16 HI only (x32) ----------------
// Per j16 block = 8192 halves (16 kchunks x 512): G = c*512 + lane*8 + e,
// j = j16*16 + (lane&15), k = c*32 + (lane>>4)*8 + e.
__global__ __launch_bounds__(256) void vq_prepB(const float* __restrict__ cb,
    unsigned short* __restrict__ Bf) {
    int j16 = blockIdx.x;                  // 64 blocks
    int t = threadIdx.x;
#pragma unroll
    for (int s = 0; s < 4; ++s) {
        int G = ((s << 8) + t) << 3;
        int c = G >> 9, w = G & 511;
        int lane = w >> 3;
        int j = (j16 << 4) + (lane & 15);
        int k0 = (c << 5) + ((lane >> 4) << 3);
        const float* p = cb + ((long)j << 9) + k0;
        unsigned short o8[8];
#pragma unroll
        for (int e = 0; e < 8; ++e) {
            H16 hh; hh.f = (_Float16)(32.f * p[e]);
            o8[e] = hh.u;
        }
        *(u32x4*)&Bf[((long)j16 << 13) + G] = *(u32x4*)&o8[0];
    }
}

// ---------------- pack: z -> Ah[m][k] fp16 hi (x32) + ||z||^2 block partials ----------------
__global__ __launch_bounds__(256) void vq_pack(const float* __restrict__ z,
    unsigned short* __restrict__ Ah,
    float* __restrict__ zpart, int base_b, int bid0) {
    __shared__ float T[64][65];
    __shared__ float ps[4];
    int bid = blockIdx.x;
    int hw0 = (bid & 63) << 6;
    int c0 = ((bid >> 6) & 7) << 6;
    int bb = (bid >> 9) + base_b;
    int t = threadIdx.x;
    int hl = t & 63, cl = t >> 6;
    const float* zp = z + ((long)((bb << 9) + c0 + cl)) * 4096 + hw0 + hl;
#pragma unroll
    for (int i = 0; i < 16; ++i)
        T[cl + 4 * i][hl] = zp[(long)(4 * i) * 4096];
    __syncthreads();
    int hr = t >> 2, cg = (t & 3) << 4;
    long m = ((long)(bb - base_b) << 12) + hw0 + hr;
    unsigned short h8[16];
    float s = 0.f;
#pragma unroll
    for (int e = 0; e < 16; ++e) {
        float v0 = T[cg + e][hr];
        s += v0 * v0;
        H16 hh; hh.f = (_Float16)(32.f * v0);
        h8[e] = hh.u;
    }
    long o = m * 512 + c0 + cg;
    *(u32x4*)&Ah[o]     = *(u32x4*)&h8[0];
    *(u32x4*)&Ah[o + 8] = *(u32x4*)&h8[8];
#pragma unroll
    for (int off = 32; off > 0; off >>= 1) s += __shfl_xor(s, off);
    if ((t & 63) == 0) ps[t >> 6] = s;
    __syncthreads();
    if (t == 0) zpart[bid0 + bid] = ps[0] + ps[1] + ps[2] + ps[3];
}

// ---------------- dist: hi-only MFMA GEMM + fused lean top-2 argmin ----------------
// Round-13 structure (validated): 256 threads / 4 waves on the same 64 m-rows; wave wid
// owns j16 quad wid*4..+3 per pass. Block tile 64m x 256j, 4 passes x 8 chunk-PAIRS.
// A-hi double-buffered LDS (2x8 KB) via global_load_lds; B-hi register fragments from L2.
// Top-2 tracking is LEAN (round-14-validated): no pass-1 tie-breaks — ties give gap=0
// which always triggers the fp32 refine (which carries the np tie-break).
__global__ __launch_bounds__(256, 4) void vq_dist(
    const unsigned short* __restrict__ Ah, const unsigned short* __restrict__ Bf,
    const float* __restrict__ ynorm, int* __restrict__ ws_idx,
    float* __restrict__ out_idx, float* __restrict__ bd1g,
    float* __restrict__ bd2g, int* __restrict__ bj2g, int mbase) {

    __shared__ _Float16 sA[2][64][64];   // 16 KB
    __shared__ float b1d[256], b2d[256];
    __shared__ int   b1j[256], b2j[256];

    const int t = threadIdx.x;
    const int l = t & 63, wid = t >> 6;
    const int lid = l & 15, kg = l >> 4;
    const int m0 = blockIdx.x << 6;

    // A staging map: lane l -> row r8 = l>>3, LDS slot sl = l&7; source slot st = sl^r8.
    const int r8 = l >> 3, sl = l & 7, st = sl ^ r8;
    const unsigned short* gpA0 = Ah + ((long)(m0 + (wid << 3) + r8) << 9)
                                    + ((st & 4) << 3) + ((st & 3) << 3);

    auto STAGE = [&](int buf, int cpair) {
        const long ao = (long)cpair << 6;              // 2 chunks = 64 halves
#pragma unroll
        for (int g = 0; g < 2; ++g)                    // 32-row stride = 1<<14 halves
            GLDS(gpA0 + ao + ((long)g << 14), &sA[buf][(wid + (g << 2)) << 3][0]);
    };

    f32x4 acc[4][4];
    auto ZERO = [&]() {
#pragma unroll
        for (int mt = 0; mt < 4; ++mt)
#pragma unroll
            for (int jt = 0; jt < 4; ++jt) acc[mt][jt] = {0.f, 0.f, 0.f, 0.f};
    };

    auto COMPUTE = [&](int buf, int sub, int c, int p) {
        half8 ah[4];
        const int q0 = sub << 2;
#pragma unroll
        for (int mt = 0; mt < 4; ++mt) {
            int row = (mt << 4) + lid;
            ah[mt] = *(const half8*)&sA[buf][row][((q0 + kg) ^ (row & 7)) << 3];
        }
        long fb = (((long)(((p << 4) + (wid << 2)) << 4) + c) << 9) + (l << 3);
        const unsigned short* bp = Bf + fb;
#pragma unroll
        for (int jt = 0; jt < 4; ++jt) {
            half8 bh = *(const half8*)(bp);
            bp += 8192;                                // next j16: 16 chunks * 512
#pragma unroll
            for (int mt = 0; mt < 4; ++mt)
                acc[mt][jt] = __builtin_amdgcn_mfma_f32_16x16x32_f16(ah[mt], bh, acc[mt][jt], 0, 0, 0);
        }
    };

    auto FOLD = [&](int p) {
        const int jgb = (p << 8) + (wid << 6);
        float yn[4];
#pragma unroll
        for (int jt = 0; jt < 4; ++jt) yn[jt] = ynorm[jgb + (jt << 4) + lid];
#pragma unroll
        for (int mt = 0; mt < 4; ++mt)
#pragma unroll
            for (int r = 0; r < 4; ++r) {
                float d1 = 3.4e38f, d2 = 3.4e38f;
                int i1 = 0x7fffffff, i2 = 0x7fffffff;
#pragma unroll
                for (int jt = 0; jt < 4; ++jt) {
                    int jg = jgb + (jt << 4) + lid;
                    float d = yn[jt] - 2.f * acc[mt][jt][r];
                    bool w = d < d1;
                    float c2 = w ? d1 : d;  int c2i = w ? i1 : jg;
                    d1 = w ? d : d1;        i1 = w ? jg : i1;
                    bool u = c2 < d2;
                    d2 = u ? c2 : d2;       i2 = u ? c2i : i2;
                }
#pragma unroll
                for (int off = 1; off < 16; off <<= 1) {
                    float e1 = __shfl_xor(d1, off), e2 = __shfl_xor(d2, off);
                    int   k1 = __shfl_xor(i1, off), k2 = __shfl_xor(i2, off);
                    bool w = e1 < d1;
                    float mx = w ? d1 : e1;  int nx = w ? i1 : k1;
                    d1 = w ? e1 : d1;        i1 = w ? k1 : i1;
                    bool a = e2 < d2;  float mm = a ? e2 : d2;  int nm = a ? k2 : i2;
                    bool bb = mx < mm;
                    d2 = bb ? mx : mm;  i2 = bb ? nx : nm;
                }
                if (lid == 0) {
                    int slot = (((mt << 4) + (kg << 2) + r) << 2) + wid;
                    float D1 = b1d[slot], D2 = b2d[slot];
                    int   J1 = b1j[slot], J2 = b2j[slot];
                    bool w = d1 < D1;
                    float mx = w ? D1 : d1;  int nx = w ? J1 : i1;
                    float N1 = w ? d1 : D1;  int NJ1 = w ? i1 : J1;
                    bool a = d2 < D2;  float mm = a ? d2 : D2;  int nm = a ? i2 : J2;
                    bool bb = mx < mm;
                    b1d[slot] = N1;            b1j[slot] = NJ1;
                    b2d[slot] = bb ? mx : mm;  b2j[slot] = bb ? nx : nm;
                }
            }
    };

    b1d[t] = 3.4e38f; b2d[t] = 3.4e38f;
    b1j[t] = 0x7fffffff; b2j[t] = 0x7fffffff;
    ZERO();
    STAGE(0, 0);
    __syncthreads();                        // chunk-pair 0 staged + LDS init visible

    int buf = 0;
    for (int cp = 0; cp < 32; ++cp) {       // 4 passes x 8 pairs, 1 barrier/pair
        int p = cp >> 3, pc = cp & 7;
        if (cp < 31) STAGE(buf ^ 1, (cp + 1) & 7);   // A repeats every pass
        COMPUTE(buf, 0, (pc << 1),     p);
        COMPUTE(buf, 1, (pc << 1) + 1, p);
        if (pc == 7) { FOLD(p); ZERO(); }
        __syncthreads();                    // vmcnt drain covered by COMPUTE
        buf ^= 1;
    }

    // final merge across 4 wave slots (one thread per m row) + writeout
    if (t < 64) {
        float D1 = 3.4e38f, D2 = 3.4e38f;
        int   J1 = 0x7fffffff, J2 = 0x7fffffff;
#pragma unroll
        for (int w2 = 0; w2 < 4; ++w2) {
            int slot = (t << 2) + w2;
            float e1 = b1d[slot], e2 = b2d[slot];
            int   k1 = b1j[slot], k2 = b2j[slot];
            bool w = e1 < D1;
            float mx = w ? D1 : e1;  int nx = w ? J1 : k1;
            D1 = w ? e1 : D1;        J1 = w ? k1 : J1;
            bool a = e2 < D2;  float mm = a ? e2 : D2;  int nm = a ? k2 : J2;
            bool bb = mx < mm;
            D2 = bb ? mx : mm;  J2 = bb ? nx : nm;
        }
        int m = mbase + m0 + t;
        ws_idx[m]  = J1;
        out_idx[m] = (float)J1;
        bd1g[m] = D1;                       // scaled; missing ||z||^2 (added in final)
        bd2g[m] = D2;
        bj2g[m] = J2;
    }
}

// ---------------- refine: exact fp32 recheck of rows with hi-only gap <= DELTA ----------------
__global__ __launch_bounds__(256) void vq_refine(const float* __restrict__ z,
    const float* __restrict__ cb, const float* __restrict__ ynorm,
    const float* __restrict__ bd2, const int* __restrict__ bj2,
    int* __restrict__ ws_idx, float* __restrict__ out_idx, float* __restrict__ bd1) {
    int l = threadIdx.x & 63;
    int wv = (blockIdx.x << 2) + (threadIdx.x >> 6);   // 4096 waves
    for (int m = wv; m < NVEC; m += 4096) {
        float d1 = bd1[m];
        if (bd2[m] - d1 > DELTA) continue;             // certain: keep pass-1 result
        int j1 = ws_idx[m], j2 = bj2[m];
        const float* zr = z + ((long)(m >> 12) << 21) + (m & 4095);
        const float* c1 = cb + ((long)j1 << 9);
        const float* c2 = cb + ((long)j2 << 9);
        float s1 = 0.f, s2 = 0.f;
#pragma unroll
        for (int e = 0; e < 8; ++e) {
            int c = (l << 3) + e;
            float a = zr[(long)c << 12];
            s1 = fmaf(a, c1[c], s1);
            s2 = fmaf(a, c2[c], s2);
        }
#pragma unroll
        for (int off = 32; off > 0; off >>= 1) {
            s1 += __shfl_xor(s1, off);
            s2 += __shfl_xor(s2, off);
        }
        float de1 = ynorm[j1] - 2048.f * s1;           // scaled: 1024*(||y||^2 - 2 z.y)
        float de2 = ynorm[j2] - 2048.f * s2;
        bool take2 = de2 < de1 || (de2 == de1 && j2 < j1);   // np first-occurrence tie-break
        if (l == 0) {
            if (take2) { ws_idx[m] = j2; out_idx[m] = (float)j2; bd1[m] = de2; }
            else       { bd1[m] = de1; }
        }
    }
}

// ---------------- gather: pure scatter of codebook rows into (B,C,H,W) ----------------
__global__ __launch_bounds__(256) void vq_gather(const float* __restrict__ cb,
    const int* __restrict__ ws_idx, float* __restrict__ out) {
    int base = blockIdx.x * 256 + threadIdx.x;   // 2^21 threads
    int hw  = base & 4095;
    int c4g = (base >> 12) & 31;
    int b   = base >> 17;
    int j   = ws_idx[(b << 12) | hw];
#pragma unroll
    for (int it = 0; it < 4; ++it) {
        int c4 = (c4g << 2) + it;
        float4 v = ((const float4*)cb)[(j << 7) + c4];
        long zo = ((long)((b << 9) + (c4 << 2))) * 4096 + hw;
        out[zo] = v.x; out[zo + 4096] = v.y; out[zo + 8192] = v.z; out[zo + 12288] = v.w;
    }
}

// ---------------- final: loss = 1.25 * (sum(bd1)/1024 + sum||z||^2) / numel ----------------
__global__ __launch_bounds__(1024) void vq_final(const float* __restrict__ bd1,
    const float* __restrict__ zpart, float* __restrict__ out) {
    int t = threadIdx.x;
    double s = 0.0;
#pragma unroll
    for (int i = 0; i < 64; ++i) s += (double)bd1[t + (i << 10)];
    s *= (1.0 / 1024.0);
#pragma unroll
    for (int i = 0; i < 8; ++i) s += (double)zpart[t + (i << 10)];
#pragma unroll
    for (int off = 32; off > 0; off >>= 1) s += __shfl_xor(s, off);
    __shared__ double pd[16];
    if ((t & 63) == 0) pd[t >> 6] = s;
    __syncthreads();
    if (t == 0) {
        double tot = 0.0;
#pragma unroll
        for (int i = 0; i < 16; ++i) tot += pd[i];
        out[ZQ_ELEMS] = (float)(1.25 * tot / 33554432.0);
    }
}

extern "C" void kernel_launch(void* const* d_in, const int* in_sizes, int n_in,
                              void* d_out, int out_size, void* d_ws, size_t ws_size,
                              hipStream_t stream) {
    const float* z  = (const float*)d_in[0];   // (16,512,64,64) fp32
    const float* cb = (const float*)d_in[1];   // (1024,512) fp32
    float* out = (float*)d_out;                // [z_q | loss | indices(float)]
    char* ws = (char*)d_ws;

    float* ynorm = (float*)(ws + 1024);                   // 4 KB
    int*   ws_idx = (int*)(ws + 8192);                    // 256 KB
    float* bd1   = (float*)(ws + 272 * 1024);             // 256 KB
    float* bd2   = (float*)(ws + 528 * 1024);             // 256 KB
    int*   bj2   = (int*)(ws + 784 * 1024);               // 256 KB
    float* zpart = (float*)(ws + 1040 * 1024);            // 32 KB
    unsigned short* Bf = (unsigned short*)(ws + (2L << 20));   // 1 MB hi-only
    const size_t base = 4L << 20;
    unsigned short* Ah = (unsigned short*)(ws + base);

    // pick M-phasing from available workspace (deterministic in ws_size)
    int nphase = 1;
    while (nphase < 16) {
        size_t Asz = (size_t)(65536 / nphase) * 512 * 2;  // hi-only bytes
        if (base + Asz <= ws_size) break;
        nphase <<= 1;
    }

    vq_prep<<<N_E, 64, 0, stream>>>(cb, ynorm);
    vq_prepB<<<64, 256, 0, stream>>>(cb, Bf);
    int PM = 65536 / nphase;
    for (int p = 0; p < nphase; ++p) {
        vq_pack<<<8192 / nphase, 256, 0, stream>>>(z, Ah, zpart,
                                                   p * (16 / nphase),
                                                   p * (8192 / nphase));
        vq_dist<<<PM / 64, 256, 0, stream>>>(Ah, Bf, ynorm, ws_idx,
                                             out + ZQ_ELEMS + 1, bd1, bd2, bj2, p * PM);
    }
    vq_refine<<<1024, 256, 0, stream>>>(z, cb, ynorm, bd2, bj2, ws_idx,
                                        out + ZQ_ELEMS + 1, bd1);
    vq_gather<<<NVEC / 256 * 32, 256, 0, stream>>>(cb, ws_idx, out);
    vq_final<<<1, 1024, 0, stream>>>(bd1, zpart, out);
}

// Round 16
// 192.326 us; speedup vs baseline: 1.8263x; 1.0746x over previous
//
#include <hip/hip_runtime.h>

#define N_E   1024
#define E_DIM 512
#define HW_   4096
#define NVEC  65536                 // 16 * 64 * 64
#define ZQ_ELEMS 33554432           // 16*512*64*64
#define BETA 0.25f
#define DELTA 384.0f                // scaled refine margin: 256 (hi-only err) + 128 (key packing)

typedef _Float16 half8 __attribute__((ext_vector_type(8), aligned(16)));
typedef float f32x4 __attribute__((ext_vector_type(4)));
typedef unsigned int u32x4 __attribute__((ext_vector_type(4), aligned(16)));

union H16 { _Float16 f; unsigned short u; };

// pack index j (10 bits) into low mantissa bits of positive distance d:
// order preserved up to +-1023 ulp (~64 scaled units), absorbed by DELTA.
__device__ __forceinline__ float PK(float d, int j) {
    return __int_as_float((__float_as_int(d) & ~1023) | j);
}

// direct-to-LDS DMA: per-lane global src, wave-uniform LDS base + lane*16
#define GLDS(gp, lp) __builtin_amdgcn_global_load_lds( \
    (const __attribute__((address_space(1))) void*)(gp), \
    (__attribute__((address_space(3))) void*)(lp), 16, 0, 0)

// ---------------- ynorm (coalesced row reduce) ----------------
__global__ __launch_bounds__(64) void vq_prep(const float* __restrict__ cb,
    float* __restrict__ ynorm) {
    int j = blockIdx.x, l = threadIdx.x;
    float s = 0.f;
    for (int i = 0; i < 8; ++i) {
        float v = cb[(j << 9) + l + (i << 6)];
        s += v * v;
    }
#pragma unroll
    for (int off = 32; off > 0; off >>= 1) s += __shfl_xor(s, off);
    if (l == 0) ynorm[j] = s * 1024.f;        // scaled by 32^2 to match scaled dot
}

// ---------------- prepB: codebook -> Bf fragment-major fp16 HI only (x32) ----------------
// Per j16 block = 8192 halves (16 kchunks x 512): G = c*512 + lane*8 + e,
// j = j16*16 + (lane&15), k = c*32 + (lane>>4)*8 + e.
__global__ __launch_bounds__(256) void vq_prepB(const float* __restrict__ cb,
    unsigned short* __restrict__ Bf) {
    int j16 = blockIdx.x;                  // 64 blocks
    int t = threadIdx.x;
#pragma unroll
    for (int s = 0; s < 4; ++s) {
        int G = ((s << 8) + t) << 3;
        int c = G >> 9, w = G & 511;
        int lane = w >> 3;
        int j = (j16 << 4) + (lane & 15);
        int k0 = (c << 5) + ((lane >> 4) << 3);
        const float* p = cb + ((long)j << 9) + k0;
        unsigned short o8[8];
#pragma unroll
        for (int e = 0; e < 8; ++e) {
            H16 hh; hh.f = (_Float16)(32.f * p[e]);
            o8[e] = hh.u;
        }
        *(u32x4*)&Bf[((long)j16 << 13) + G] = *(u32x4*)&o8[0];
    }
}

// ---------------- pack: z -> Ah[m][k] fp16 hi (x32) + ||z||^2 block partials ----------------
__global__ __launch_bounds__(256) void vq_pack(const float* __restrict__ z,
    unsigned short* __restrict__ Ah,
    float* __restrict__ zpart, int base_b, int bid0) {
    __shared__ float T[64][65];
    __shared__ float ps[4];
    int bid = blockIdx.x;
    int hw0 = (bid & 63) << 6;
    int c0 = ((bid >> 6) & 7) << 6;
    int bb = (bid >> 9) + base_b;
    int t = threadIdx.x;
    int hl = t & 63, cl = t >> 6;
    const float* zp = z + ((long)((bb << 9) + c0 + cl)) * 4096 + hw0 + hl;
#pragma unroll
    for (int i = 0; i < 16; ++i)
        T[cl + 4 * i][hl] = zp[(long)(4 * i) * 4096];
    __syncthreads();
    int hr = t >> 2, cg = (t & 3) << 4;
    long m = ((long)(bb - base_b) << 12) + hw0 + hr;
    unsigned short h8[16];
    float s = 0.f;
#pragma unroll
    for (int e = 0; e < 16; ++e) {
        float v0 = T[cg + e][hr];
        s += v0 * v0;
        H16 hh; hh.f = (_Float16)(32.f * v0);
        h8[e] = hh.u;
    }
    long o = m * 512 + c0 + cg;
    *(u32x4*)&Ah[o]     = *(u32x4*)&h8[0];
    *(u32x4*)&Ah[o + 8] = *(u32x4*)&h8[8];
#pragma unroll
    for (int off = 32; off > 0; off >>= 1) s += __shfl_xor(s, off);
    if ((t & 63) == 0) ps[t >> 6] = s;
    __syncthreads();
    if (t == 0) zpart[bid0 + bid] = ps[0] + ps[1] + ps[2] + ps[3];
}

// ---------------- dist: hi-only MFMA GEMM + packed-key top-2 argmin ----------------
// Round-13/15 structure (validated): 256 threads / 4 waves on the same 64 m-rows;
// wave wid owns j16 quad wid*4..+3 per pass. Block tile 64m x 256j, 4 passes x 8 pairs.
// A-hi double-buffered LDS (2x8 KB) via global_load_lds; B-hi register fragments from L2.
// Top-2 on PACKED float keys (index in low mantissa bits): pure v_min/v_max chains.
__global__ __launch_bounds__(256, 4) void vq_dist(
    const unsigned short* __restrict__ Ah, const unsigned short* __restrict__ Bf,
    const float* __restrict__ ynorm, int* __restrict__ ws_idx,
    float* __restrict__ out_idx, float* __restrict__ bd1g,
    float* __restrict__ bd2g, int* __restrict__ bj2g, int mbase) {

    __shared__ _Float16 sA[2][64][64];   // 16 KB
    __shared__ float b1k[256], b2k[256]; // packed-key running top-2 per (row, wid)

    const int t = threadIdx.x;
    const int l = t & 63, wid = t >> 6;
    const int lid = l & 15, kg = l >> 4;
    const int m0 = blockIdx.x << 6;

    // A staging map: lane l -> row r8 = l>>3, LDS slot sl = l&7; source slot st = sl^r8.
    const int r8 = l >> 3, sl = l & 7, st = sl ^ r8;
    const unsigned short* gpA0 = Ah + ((long)(m0 + (wid << 3) + r8) << 9)
                                    + ((st & 4) << 3) + ((st & 3) << 3);

    auto STAGE = [&](int buf, int cpair) {
        const long ao = (long)cpair << 6;              // 2 chunks = 64 halves
#pragma unroll
        for (int g = 0; g < 2; ++g)                    // 32-row stride = 1<<14 halves
            GLDS(gpA0 + ao + ((long)g << 14), &sA[buf][(wid + (g << 2)) << 3][0]);
    };

    f32x4 acc[4][4];
    auto ZERO = [&]() {
#pragma unroll
        for (int mt = 0; mt < 4; ++mt)
#pragma unroll
            for (int jt = 0; jt < 4; ++jt) acc[mt][jt] = {0.f, 0.f, 0.f, 0.f};
    };

    auto COMPUTE = [&](int buf, int sub, int c, int p) {
        half8 ah[4];
        const int q0 = sub << 2;
#pragma unroll
        for (int mt = 0; mt < 4; ++mt) {
            int row = (mt << 4) + lid;
            ah[mt] = *(const half8*)&sA[buf][row][((q0 + kg) ^ (row & 7)) << 3];
        }
        long fb = (((long)(((p << 4) + (wid << 2)) << 4) + c) << 9) + (l << 3);
        const unsigned short* bp = Bf + fb;
#pragma unroll
        for (int jt = 0; jt < 4; ++jt) {
            half8 bh = *(const half8*)(bp);
            bp += 8192;                                // next j16: 16 chunks * 512
#pragma unroll
            for (int mt = 0; mt < 4; ++mt)
                acc[mt][jt] = __builtin_amdgcn_mfma_f32_16x16x32_f16(ah[mt], bh, acc[mt][jt], 0, 0, 0);
        }
    };

    auto FOLD = [&](int p) {
        const int jgb = (p << 8) + (wid << 6);
        float yn[4]; int jg[4];
#pragma unroll
        for (int jt = 0; jt < 4; ++jt) {
            jg[jt] = jgb + (jt << 4) + lid;
            yn[jt] = ynorm[jg[jt]];
        }
#pragma unroll
        for (int mt = 0; mt < 4; ++mt)
#pragma unroll
            for (int r = 0; r < 4; ++r) {
                float k0 = PK(yn[0] - 2.f * acc[mt][0][r], jg[0]);
                float k1 = PK(yn[1] - 2.f * acc[mt][1][r], jg[1]);
                float k2 = PK(yn[2] - 2.f * acc[mt][2][r], jg[2]);
                float k3 = PK(yn[3] - 2.f * acc[mt][3][r], jg[3]);
                // top-2 of 4
                float m1 = fminf(k0, k1), M1 = fmaxf(k0, k1);
                float m2 = fminf(k2, k3), M2 = fmaxf(k2, k3);
                float best = fminf(m1, m2);
                float sec  = fminf(fmaxf(m1, m2), fminf(M1, M2));
                // cross-lane over the 16 j-columns
#pragma unroll
                for (int off = 1; off < 16; off <<= 1) {
                    float e1 = __shfl_xor(best, off);
                    float e2 = __shfl_xor(sec, off);
                    sec  = fminf(fminf(sec, e2), fmaxf(best, e1));
                    best = fminf(best, e1);
                }
                if (lid == 0) {
                    int slot = (((mt << 4) + (kg << 2) + r) << 2) + wid;
                    float B1 = b1k[slot], B2 = b2k[slot];
                    b2k[slot] = fminf(fminf(B2, sec), fmaxf(B1, best));
                    b1k[slot] = fminf(B1, best);
                }
            }
    };

    b1k[t] = 3.4e38f; b2k[t] = 3.4e38f;
    ZERO();
    STAGE(0, 0);
    __syncthreads();                        // chunk-pair 0 staged + LDS init visible

    int buf = 0;
    for (int cp = 0; cp < 32; ++cp) {       // 4 passes x 8 pairs, 1 barrier/pair
        int p = cp >> 3, pc = cp & 7;
        if (cp < 31) STAGE(buf ^ 1, (cp + 1) & 7);   // A repeats every pass
        COMPUTE(buf, 0, (pc << 1),     p);
        COMPUTE(buf, 1, (pc << 1) + 1, p);
        if (pc == 7) { FOLD(p); ZERO(); }
        __syncthreads();                    // vmcnt drain covered by COMPUTE
        buf ^= 1;
    }

    // final merge across 4 wave slots (one thread per m row) + unpack + writeout
    if (t < 64) {
        float K1 = 3.4e38f, K2 = 3.4e38f;
#pragma unroll
        for (int w2 = 0; w2 < 4; ++w2) {
            int slot = (t << 2) + w2;
            float e1 = b1k[slot], e2 = b2k[slot];
            K2 = fminf(fminf(K2, e2), fmaxf(K1, e1));
            K1 = fminf(K1, e1);
        }
        int m = mbase + m0 + t;
        int u1 = __float_as_int(K1), u2 = __float_as_int(K2);
        int J1 = u1 & 1023, J2 = u2 & 1023;
        ws_idx[m]  = J1;
        out_idx[m] = (float)J1;
        bd1g[m] = __int_as_float(u1 & ~1023);   // scaled; missing ||z||^2 (added in final)
        bd2g[m] = __int_as_float(u2 & ~1023);
        bj2g[m] = J2;
    }
}

// ---------------- refine: exact fp32 recheck of rows with hi-only gap <= DELTA ----------------
__global__ __launch_bounds__(256) void vq_refine(const float* __restrict__ z,
    const float* __restrict__ cb, const float* __restrict__ ynorm,
    const float* __restrict__ bd2, const int* __restrict__ bj2,
    int* __restrict__ ws_idx, float* __restrict__ out_idx, float* __restrict__ bd1) {
    int l = threadIdx.x & 63;
    int wv = (blockIdx.x << 2) + (threadIdx.x >> 6);   // 4096 waves
    for (int m = wv; m < NVEC; m += 4096) {
        float d1 = bd1[m];
        if (bd2[m] - d1 > DELTA) continue;             // certain: keep pass-1 result
        int j1 = ws_idx[m], j2 = bj2[m];
        const float* zr = z + ((long)(m >> 12) << 21) + (m & 4095);
        const float* c1 = cb + ((long)j1 << 9);
        const float* c2 = cb + ((long)j2 << 9);
        float s1 = 0.f, s2 = 0.f;
#pragma unroll
        for (int e = 0; e < 8; ++e) {
            int c = (l << 3) + e;
            float a = zr[(long)c << 12];
            s1 = fmaf(a, c1[c], s1);
            s2 = fmaf(a, c2[c], s2);
        }
#pragma unroll
        for (int off = 32; off > 0; off >>= 1) {
            s1 += __shfl_xor(s1, off);
            s2 += __shfl_xor(s2, off);
        }
        float de1 = ynorm[j1] - 2048.f * s1;           // scaled: 1024*(||y||^2 - 2 z.y)
        float de2 = ynorm[j2] - 2048.f * s2;
        bool take2 = de2 < de1 || (de2 == de1 && j2 < j1);   // np first-occurrence tie-break
        if (l == 0) {
            if (take2) { ws_idx[m] = j2; out_idx[m] = (float)j2; bd1[m] = de2; }
            else       { bd1[m] = de1; }
        }
    }
}

// ---------------- gather: pure scatter of codebook rows into (B,C,H,W) ----------------
__global__ __launch_bounds__(256) void vq_gather(const float* __restrict__ cb,
    const int* __restrict__ ws_idx, float* __restrict__ out) {
    int base = blockIdx.x * 256 + threadIdx.x;   // 2^21 threads
    int hw  = base & 4095;
    int c4g = (base >> 12) & 31;
    int b   = base >> 17;
    int j   = ws_idx[(b << 12) | hw];
#pragma unroll
    for (int it = 0; it < 4; ++it) {
        int c4 = (c4g << 2) + it;
        float4 v = ((const float4*)cb)[(j << 7) + c4];
        long zo = ((long)((b << 9) + (c4 << 2))) * 4096 + hw;
        out[zo] = v.x; out[zo + 4096] = v.y; out[zo + 8192] = v.z; out[zo + 12288] = v.w;
    }
}

// ---------------- final: loss = 1.25 * (sum(bd1)/1024 + sum||z||^2) / numel ----------------
__global__ __launch_bounds__(1024) void vq_final(const float* __restrict__ bd1,
    const float* __restrict__ zpart, float* __restrict__ out) {
    int t = threadIdx.x;
    double s = 0.0;
#pragma unroll
    for (int i = 0; i < 64; ++i) s += (double)bd1[t + (i << 10)];
    s *= (1.0 / 1024.0);
#pragma unroll
    for (int i = 0; i < 8; ++i) s += (double)zpart[t + (i << 10)];
#pragma unroll
    for (int off = 32; off > 0; off >>= 1) s += __shfl_xor(s, off);
    __shared__ double pd[16];
    if ((t & 63) == 0) pd[t >> 6] = s;
    __syncthreads();
    if (t == 0) {
        double tot = 0.0;
#pragma unroll
        for (int i = 0; i < 16; ++i) tot += pd[i];
        out[ZQ_ELEMS] = (float)(1.25 * tot / 33554432.0);
    }
}

extern "C" void kernel_launch(void* const* d_in, const int* in_sizes, int n_in,
                              void* d_out, int out_size, void* d_ws, size_t ws_size,
                              hipStream_t stream) {
    const float* z  = (const float*)d_in[0];   // (16,512,64,64) fp32
    const float* cb = (const float*)d_in[1];   // (1024,512) fp32
    float* out = (float*)d_out;                // [z_q | loss | indices(float)]
    char* ws = (char*)d_ws;

    float* ynorm = (float*)(ws + 1024);                   // 4 KB
    int*   ws_idx = (int*)(ws + 8192);                    // 256 KB
    float* bd1   = (float*)(ws + 272 * 1024);             // 256 KB
    float* bd2   = (float*)(ws + 528 * 1024);             // 256 KB
    int*   bj2   = (int*)(ws + 784 * 1024);               // 256 KB
    float* zpart = (float*)(ws + 1040 * 1024);            // 32 KB
    unsigned short* Bf = (unsigned short*)(ws + (2L << 20));   // 1 MB hi-only
    const size_t base = 4L << 20;
    unsigned short* Ah = (unsigned short*)(ws + base);

    // pick M-phasing from available workspace (deterministic in ws_size)
    int nphase = 1;
    while (nphase < 16) {
        size_t Asz = (size_t)(65536 / nphase) * 512 * 2;  // hi-only bytes
        if (base + Asz <= ws_size) break;
        nphase <<= 1;
    }

    vq_prep<<<N_E, 64, 0, stream>>>(cb, ynorm);
    vq_prepB<<<64, 256, 0, stream>>>(cb, Bf);
    int PM = 65536 / nphase;
    for (int p = 0; p < nphase; ++p) {
        vq_pack<<<8192 / nphase, 256, 0, stream>>>(z, Ah, zpart,
                                                   p * (16 / nphase),
                                                   p * (8192 / nphase));
        vq_dist<<<PM / 64, 256, 0, stream>>>(Ah, Bf, ynorm, ws_idx,
                                             out + ZQ_ELEMS + 1, bd1, bd2, bj2, p * PM);
    }
    vq_refine<<<1024, 256, 0, stream>>>(z, cb, ynorm, bd2, bj2, ws_idx,
                                        out + ZQ_ELEMS + 1, bd1);
    vq_gather<<<NVEC / 256 * 32, 256, 0, stream>>>(cb, ws_idx, out);
    vq_final<<<1, 1024, 0, stream>>>(bd1, zpart, out);
}

// Round 17
// 192.246 us; speedup vs baseline: 1.8271x; 1.0004x over previous
//
#include <hip/hip_runtime.h>

#define N_E   1024
#define E_DIM 512
#define HW_   4096
#define NVEC  65536                 // 16 * 64 * 64
#define ZQ_ELEMS 33554432           // 16*512*64*64
#define BETA 0.25f
#define DELTA 384.0f                // scaled refine margin: 256 (hi-only err) + 128 (key packing)

typedef _Float16 half8 __attribute__((ext_vector_type(8), aligned(16)));
typedef float f32x4 __attribute__((ext_vector_type(4)));
typedef unsigned int u32x4 __attribute__((ext_vector_type(4), aligned(16)));

union H16 { _Float16 f; unsigned short u; };

// pack index j (10 bits) into low mantissa bits of positive distance d:
// order preserved up to +-1023 ulp (~64 scaled units), absorbed by DELTA.
__device__ __forceinline__ float PK(float d, int j) {
    return __int_as_float((__float_as_int(d) & ~1023) | j);
}

// direct-to-LDS DMA: per-lane global src, wave-uniform LDS base + lane*16
#define GLDS(gp, lp) __builtin_amdgcn_global_load_lds( \
    (const __attribute__((address_space(1))) void*)(gp), \
    (__attribute__((address_space(3))) void*)(lp), 16, 0, 0)

// ---------------- ynorm (coalesced row reduce) ----------------
__global__ __launch_bounds__(64) void vq_prep(const float* __restrict__ cb,
    float* __restrict__ ynorm) {
    int j = blockIdx.x, l = threadIdx.x;
    float s = 0.f;
    for (int i = 0; i < 8; ++i) {
        float v = cb[(j << 9) + l + (i << 6)];
        s += v * v;
    }
#pragma unroll
    for (int off = 32; off > 0; off >>= 1) s += __shfl_xor(s, off);
    if (l == 0) ynorm[j] = s * 1024.f;        // scaled by 32^2 to match scaled dot
}

// ---------------- prepB: codebook -> Bf fragment-major fp16 HI only (x32) ----------------
// Per j16 block = 8192 halves (16 kchunks x 512): G = c*512 + lane*8 + e,
// j = j16*16 + (lane&15), k = c*32 + (lane>>4)*8 + e.
__global__ __launch_bounds__(256) void vq_prepB(const float* __restrict__ cb,
    unsigned short* __restrict__ Bf) {
    int j16 = blockIdx.x;                  // 64 blocks
    int t = threadIdx.x;
#pragma unroll
    for (int s = 0; s < 4; ++s) {
        int G = ((s << 8) + t) << 3;
        int c = G >> 9, w = G & 511;
        int lane = w >> 3;
        int j = (j16 << 4) + (lane & 15);
        int k0 = (c << 5) + ((lane >> 4) << 3);
        const float* p = cb + ((long)j << 9) + k0;
        unsigned short o8[8];
#pragma unroll
        for (int e = 0; e < 8; ++e) {
            H16 hh; hh.f = (_Float16)(32.f * p[e]);
            o8[e] = hh.u;
        }
        *(u32x4*)&Bf[((long)j16 << 13) + G] = *(u32x4*)&o8[0];
    }
}

// ---------------- pack: z -> Ah[m][k] fp16 hi (x32) + ||z||^2 block partials ----------------
__global__ __launch_bounds__(256) void vq_pack(const float* __restrict__ z,
    unsigned short* __restrict__ Ah,
    float* __restrict__ zpart, int base_b, int bid0) {
    __shared__ float T[64][65];
    __shared__ float ps[4];
    int bid = blockIdx.x;
    int hw0 = (bid & 63) << 6;
    int c0 = ((bid >> 6) & 7) << 6;
    int bb = (bid >> 9) + base_b;
    int t = threadIdx.x;
    int hl = t & 63, cl = t >> 6;
    const float* zp = z + ((long)((bb << 9) + c0 + cl)) * 4096 + hw0 + hl;
#pragma unroll
    for (int i = 0; i < 16; ++i)
        T[cl + 4 * i][hl] = zp[(long)(4 * i) * 4096];
    __syncthreads();
    int hr = t >> 2, cg = (t & 3) << 4;
    long m = ((long)(bb - base_b) << 12) + hw0 + hr;
    unsigned short h8[16];
    float s = 0.f;
#pragma unroll
    for (int e = 0; e < 16; ++e) {
        float v0 = T[cg + e][hr];
        s += v0 * v0;
        H16 hh; hh.f = (_Float16)(32.f * v0);
        h8[e] = hh.u;
    }
    long o = m * 512 + c0 + cg;
    *(u32x4*)&Ah[o]     = *(u32x4*)&h8[0];
    *(u32x4*)&Ah[o + 8] = *(u32x4*)&h8[8];
#pragma unroll
    for (int off = 32; off > 0; off >>= 1) s += __shfl_xor(s, off);
    if ((t & 63) == 0) ps[t >> 6] = s;
    __syncthreads();
    if (t == 0) zpart[bid0 + bid] = ps[0] + ps[1] + ps[2] + ps[3];
}

// ---------------- dist: hi-only MFMA GEMM + packed-key top-2 argmin ----------------
// Round-13/15 structure (validated): 256 threads / 4 waves on the same 64 m-rows;
// wave wid owns j16 quad wid*4..+3 per pass. Block tile 64m x 256j, 4 passes x 8 pairs.
// A-hi double-buffered LDS (2x8 KB) via global_load_lds; B-hi register fragments from L2.
// Top-2 on PACKED float keys (index in low mantissa bits): pure v_min/v_max chains.
__global__ __launch_bounds__(256, 4) void vq_dist(
    const unsigned short* __restrict__ Ah, const unsigned short* __restrict__ Bf,
    const float* __restrict__ ynorm, int* __restrict__ ws_idx,
    float* __restrict__ out_idx, float* __restrict__ bd1g,
    float* __restrict__ bd2g, int* __restrict__ bj2g, int mbase) {

    __shared__ _Float16 sA[2][64][64];   // 16 KB
    __shared__ float b1k[256], b2k[256]; // packed-key running top-2 per (row, wid)

    const int t = threadIdx.x;
    const int l = t & 63, wid = t >> 6;
    const int lid = l & 15, kg = l >> 4;
    const int m0 = blockIdx.x << 6;

    // A staging map: lane l -> row r8 = l>>3, LDS slot sl = l&7; source slot st = sl^r8.
    const int r8 = l >> 3, sl = l & 7, st = sl ^ r8;
    const unsigned short* gpA0 = Ah + ((long)(m0 + (wid << 3) + r8) << 9)
                                    + ((st & 4) << 3) + ((st & 3) << 3);

    auto STAGE = [&](int buf, int cpair) {
        const long ao = (long)cpair << 6;              // 2 chunks = 64 halves
#pragma unroll
        for (int g = 0; g < 2; ++g)                    // 32-row stride = 1<<14 halves
            GLDS(gpA0 + ao + ((long)g << 14), &sA[buf][(wid + (g << 2)) << 3][0]);
    };

    f32x4 acc[4][4];
    auto ZERO = [&]() {
#pragma unroll
        for (int mt = 0; mt < 4; ++mt)
#pragma unroll
            for (int jt = 0; jt < 4; ++jt) acc[mt][jt] = {0.f, 0.f, 0.f, 0.f};
    };

    auto COMPUTE = [&](int buf, int sub, int c, int p) {
        half8 ah[4];
        const int q0 = sub << 2;
#pragma unroll
        for (int mt = 0; mt < 4; ++mt) {
            int row = (mt << 4) + lid;
            ah[mt] = *(const half8*)&sA[buf][row][((q0 + kg) ^ (row & 7)) << 3];
        }
        long fb = (((long)(((p << 4) + (wid << 2)) << 4) + c) << 9) + (l << 3);
        const unsigned short* bp = Bf + fb;
#pragma unroll
        for (int jt = 0; jt < 4; ++jt) {
            half8 bh = *(const half8*)(bp);
            bp += 8192;                                // next j16: 16 chunks * 512
#pragma unroll
            for (int mt = 0; mt < 4; ++mt)
                acc[mt][jt] = __builtin_amdgcn_mfma_f32_16x16x32_f16(ah[mt], bh, acc[mt][jt], 0, 0, 0);
        }
    };

    auto FOLD = [&](int p) {
        const int jgb = (p << 8) + (wid << 6);
        float yn[4]; int jg[4];
#pragma unroll
        for (int jt = 0; jt < 4; ++jt) {
            jg[jt] = jgb + (jt << 4) + lid;
            yn[jt] = ynorm[jg[jt]];
        }
#pragma unroll
        for (int mt = 0; mt < 4; ++mt)
#pragma unroll
            for (int r = 0; r < 4; ++r) {
                float k0 = PK(yn[0] - 2.f * acc[mt][0][r], jg[0]);
                float k1 = PK(yn[1] - 2.f * acc[mt][1][r], jg[1]);
                float k2 = PK(yn[2] - 2.f * acc[mt][2][r], jg[2]);
                float k3 = PK(yn[3] - 2.f * acc[mt][3][r], jg[3]);
                // top-2 of 4
                float m1 = fminf(k0, k1), M1 = fmaxf(k0, k1);
                float m2 = fminf(k2, k3), M2 = fmaxf(k2, k3);
                float best = fminf(m1, m2);
                float sec  = fminf(fmaxf(m1, m2), fminf(M1, M2));
                // cross-lane over the 16 j-columns
#pragma unroll
                for (int off = 1; off < 16; off <<= 1) {
                    float e1 = __shfl_xor(best, off);
                    float e2 = __shfl_xor(sec, off);
                    sec  = fminf(fminf(sec, e2), fmaxf(best, e1));
                    best = fminf(best, e1);
                }
                if (lid == 0) {
                    int slot = (((mt << 4) + (kg << 2) + r) << 2) + wid;
                    float B1 = b1k[slot], B2 = b2k[slot];
                    b2k[slot] = fminf(fminf(B2, sec), fmaxf(B1, best));
                    b1k[slot] = fminf(B1, best);
                }
            }
    };

    b1k[t] = 3.4e38f; b2k[t] = 3.4e38f;
    ZERO();
    STAGE(0, 0);
    __syncthreads();                        // chunk-pair 0 staged + LDS init visible

    int buf = 0;
    for (int cp = 0; cp < 32; ++cp) {       // 4 passes x 8 pairs, 1 barrier/pair
        int p = cp >> 3, pc = cp & 7;
        if (cp < 31) STAGE(buf ^ 1, (cp + 1) & 7);   // A repeats every pass
        COMPUTE(buf, 0, (pc << 1),     p);
        COMPUTE(buf, 1, (pc << 1) + 1, p);
        if (pc == 7) { FOLD(p); ZERO(); }
        __syncthreads();                    // vmcnt drain covered by COMPUTE
        buf ^= 1;
    }

    // final merge across 4 wave slots (one thread per m row) + unpack + writeout
    if (t < 64) {
        float K1 = 3.4e38f, K2 = 3.4e38f;
#pragma unroll
        for (int w2 = 0; w2 < 4; ++w2) {
            int slot = (t << 2) + w2;
            float e1 = b1k[slot], e2 = b2k[slot];
            K2 = fminf(fminf(K2, e2), fmaxf(K1, e1));
            K1 = fminf(K1, e1);
        }
        int m = mbase + m0 + t;
        int u1 = __float_as_int(K1), u2 = __float_as_int(K2);
        int J1 = u1 & 1023, J2 = u2 & 1023;
        ws_idx[m]  = J1;
        out_idx[m] = (float)J1;
        bd1g[m] = __int_as_float(u1 & ~1023);   // scaled; missing ||z||^2 (added in final)
        bd2g[m] = __int_as_float(u2 & ~1023);
        bj2g[m] = J2;
    }
}

// ---------------- refine: exact fp32 recheck of rows with hi-only gap <= DELTA ----------------
__global__ __launch_bounds__(256) void vq_refine(const float* __restrict__ z,
    const float* __restrict__ cb, const float* __restrict__ ynorm,
    const float* __restrict__ bd2, const int* __restrict__ bj2,
    int* __restrict__ ws_idx, float* __restrict__ out_idx, float* __restrict__ bd1) {
    int l = threadIdx.x & 63;
    int wv = (blockIdx.x << 2) + (threadIdx.x >> 6);   // 4096 waves
    for (int m = wv; m < NVEC; m += 4096) {
        float d1 = bd1[m];
        if (bd2[m] - d1 > DELTA) continue;             // certain: keep pass-1 result
        int j1 = ws_idx[m], j2 = bj2[m];
        const float* zr = z + ((long)(m >> 12) << 21) + (m & 4095);
        const float* c1 = cb + ((long)j1 << 9);
        const float* c2 = cb + ((long)j2 << 9);
        float s1 = 0.f, s2 = 0.f;
#pragma unroll
        for (int e = 0; e < 8; ++e) {
            int c = (l << 3) + e;
            float a = zr[(long)c << 12];
            s1 = fmaf(a, c1[c], s1);
            s2 = fmaf(a, c2[c], s2);
        }
#pragma unroll
        for (int off = 32; off > 0; off >>= 1) {
            s1 += __shfl_xor(s1, off);
            s2 += __shfl_xor(s2, off);
        }
        float de1 = ynorm[j1] - 2048.f * s1;           // scaled: 1024*(||y||^2 - 2 z.y)
        float de2 = ynorm[j2] - 2048.f * s2;
        bool take2 = de2 < de1 || (de2 == de1 && j2 < j1);   // np first-occurrence tie-break
        if (l == 0) {
            if (take2) { ws_idx[m] = j2; out_idx[m] = (float)j2; bd1[m] = de2; }
            else       { bd1[m] = de1; }
        }
    }
}

// ---------------- gather: pure scatter of codebook rows into (B,C,H,W) ----------------
__global__ __launch_bounds__(256) void vq_gather(const float* __restrict__ cb,
    const int* __restrict__ ws_idx, float* __restrict__ out) {
    int base = blockIdx.x * 256 + threadIdx.x;   // 2^21 threads
    int hw  = base & 4095;
    int c4g = (base >> 12) & 31;
    int b   = base >> 17;
    int j   = ws_idx[(b << 12) | hw];
#pragma unroll
    for (int it = 0; it < 4; ++it) {
        int c4 = (c4g << 2) + it;
        float4 v = ((const float4*)cb)[(j << 7) + c4];
        long zo = ((long)((b << 9) + (c4 << 2))) * 4096 + hw;
        out[zo] = v.x; out[zo + 4096] = v.y; out[zo + 8192] = v.z; out[zo + 12288] = v.w;
    }
}

// ---------------- final: loss = 1.25 * (sum(bd1)/1024 + sum||z||^2) / numel ----------------
__global__ __launch_bounds__(1024) void vq_final(const float* __restrict__ bd1,
    const float* __restrict__ zpart, float* __restrict__ out) {
    int t = threadIdx.x;
    double s = 0.0;
#pragma unroll
    for (int i = 0; i < 64; ++i) s += (double)bd1[t + (i << 10)];
    s *= (1.0 / 1024.0);
#pragma unroll
    for (int i = 0; i < 8; ++i) s += (double)zpart[t + (i << 10)];
#pragma unroll
    for (int off = 32; off > 0; off >>= 1) s += __shfl_xor(s, off);
    __shared__ double pd[16];
    if ((t & 63) == 0) pd[t >> 6] = s;
    __syncthreads();
    if (t == 0) {
        double tot = 0.0;
#pragma unroll
        for (int i = 0; i < 16; ++i) tot += pd[i];
        out[ZQ_ELEMS] = (float)(1.25 * tot / 33554432.0);
    }
}

extern "C" void kernel_launch(void* const* d_in, const int* in_sizes, int n_in,
                              void* d_out, int out_size, void* d_ws, size_t ws_size,
                              hipStream_t stream) {
    const float* z  = (const float*)d_in[0];   // (16,512,64,64) fp32
    const float* cb = (const float*)d_in[1];   // (1024,512) fp32
    float* out = (float*)d_out;                // [z_q | loss | indices(float)]
    char* ws = (char*)d_ws;

    float* ynorm = (float*)(ws + 1024);                   // 4 KB
    int*   ws_idx = (int*)(ws + 8192);                    // 256 KB
    float* bd1   = (float*)(ws + 272 * 1024);             // 256 KB
    float* bd2   = (float*)(ws + 528 * 1024);             // 256 KB
    int*   bj2   = (int*)(ws + 784 * 1024);               // 256 KB
    float* zpart = (float*)(ws + 1040 * 1024);            // 32 KB
    unsigned short* Bf = (unsigned short*)(ws + (2L << 20));   // 1 MB hi-only
    const size_t base = 4L << 20;
    unsigned short* Ah = (unsigned short*)(ws + base);

    // pick M-phasing from available workspace (deterministic in ws_size)
    int nphase = 1;
    while (nphase < 16) {
        size_t Asz = (size_t)(65536 / nphase) * 512 * 2;  // hi-only bytes
        if (base + Asz <= ws_size) break;
        nphase <<= 1;
    }

    vq_prep<<<N_E, 64, 0, stream>>>(cb, ynorm);
    vq_prepB<<<64, 256, 0, stream>>>(cb, Bf);
    int PM = 65536 / nphase;
    for (int p = 0; p < nphase; ++p) {
        vq_pack<<<8192 / nphase, 256, 0, stream>>>(z, Ah, zpart,
                                                   p * (16 / nphase),
                                                   p * (8192 / nphase));
        vq_dist<<<PM / 64, 256, 0, stream>>>(Ah, Bf, ynorm, ws_idx,
                                             out + ZQ_ELEMS + 1, bd1, bd2, bj2, p * PM);
    }
    vq_refine<<<1024, 256, 0, stream>>>(z, cb, ynorm, bd2, bj2, ws_idx,
                                        out + ZQ_ELEMS + 1, bd1);
    vq_gather<<<NVEC / 256 * 32, 256, 0, stream>>>(cb, ws_idx, out);
    vq_final<<<1, 1024, 0, stream>>>(bd1, zpart, out);
}